// Round 5
// baseline (409.490 us; speedup 1.0000x reference)
//
#include <hip/hip_runtime.h>

#define N_TOK 8192
#define DIM   512
#define NREL  20
#define NGRP  40   // 2R
#define OUTD  256

typedef unsigned short u16;
typedef u16    u16x8  __attribute__((ext_vector_type(8)));
typedef __bf16 bf16x8 __attribute__((ext_vector_type(8)));
typedef float  f32x4  __attribute__((ext_vector_type(4)));

__device__ __forceinline__ u16 f2bf(float f) {
  union { float f; unsigned u; } v; v.f = f;
  return (u16)((v.u + 0x7FFFu + ((v.u >> 16) & 1u)) >> 16);  // RNE
}
// XOR-swizzle of 16B chunks within a row: kills the row-stride bank pattern.
__device__ __forceinline__ int swz8(int row, int chunk) { return chunk ^ (row & 7); }

// fp32 -> bf16, vectorized (used once for x -> h0)
__global__ void k_cvt(const float* __restrict__ in, u16* __restrict__ out, int n4) {
  int stride = gridDim.x * blockDim.x;
  for (int idx = blockIdx.x * blockDim.x + threadIdx.x; idx < n4; idx += stride) {
    float4 v = reinterpret_cast<const float4*>(in)[idx];
    u16 o0 = f2bf(v.x), o1 = f2bf(v.y), o2 = f2bf(v.z), o3 = f2bf(v.w);
    u16x8 dummy; (void)dummy;
    reinterpret_cast<ushort4*>(out)[idx] = make_ushort4(o0, o1, o2, o3);
  }
}

// ---- edge bucketing by relation ----
__global__ void k_hist(const int* __restrict__ rel, int* __restrict__ cnt) {
  int e = blockIdx.x * blockDim.x + threadIdx.x;
  if (e < N_TOK) atomicAdd(&cnt[rel[e]], 1);
}
__global__ void k_scan(const int* __restrict__ cnt, int* __restrict__ off) {
  if (threadIdx.x == 0) {
    int s = 0;
    for (int r = 0; r < NREL; ++r) { off[r] = s; s += cnt[r]; }
    off[NREL] = s;
  }
}
__global__ void k_fill(const int* __restrict__ rel, const int* __restrict__ off,
                       int* __restrict__ cur, int* __restrict__ elist) {
  int e = blockIdx.x * blockDim.x + threadIdx.x;
  if (e < N_TOK) {
    int r = rel[e];
    int p = atomicAdd(&cur[r], 1);
    elist[off[r] + p] = e;
  }
}

// ---- dense GEMM: acc = A(bf16)[M,512] @ W(fp32->bf16)[Nn,512]^T ----
// MODE 1: out = bf16(relu(acc + bias + E))   (layer output, E = edge accum)
// MODE 0: out = acc + bias (fp32)            (final FF layer)
template <int MODE>
__global__ __launch_bounds__(256) void k_gemm(
    const u16* __restrict__ A, const float* __restrict__ Wf,
    const float* __restrict__ bias, const float* __restrict__ E,
    float* __restrict__ Cf, u16* __restrict__ Ch, int Nn)
{
  __shared__ u16 As[64 * 64];   // 8 KB, XOR-swizzled 16B chunks
  __shared__ u16 Bs[64 * 64];
  const int m0 = blockIdx.x * 64, n0 = blockIdx.y * 64;
  const int t = threadIdx.x;
  const int w = t >> 6, l = t & 63;
  const int wr = (w >> 1) * 32, wc = (w & 1) * 32;
  const int lc = l & 15, h8 = l >> 4;
  const int srow = t >> 2, sc2 = (t & 3) * 2;   // two 16B chunks per thread

  f32x4 acc[2][2] = {};
  const u16*   gA = A  + (size_t)(m0 + srow) * DIM + sc2 * 8;
  const float* gB = Wf + (size_t)(n0 + srow) * DIM + sc2 * 8;

  for (int k0 = 0; k0 < DIM; k0 += 64) {
    // stage A (bf16) at swizzled chunk positions
    u16x8 alo = *reinterpret_cast<const u16x8*>(gA + k0);
    u16x8 ahi = *reinterpret_cast<const u16x8*>(gA + k0 + 8);
    *reinterpret_cast<u16x8*>(&As[srow * 64 + swz8(srow, sc2)     * 8]) = alo;
    *reinterpret_cast<u16x8*>(&As[srow * 64 + swz8(srow, sc2 + 1) * 8]) = ahi;
    // stage B: fp32 -> bf16 in-register
    float4 f0 = *reinterpret_cast<const float4*>(gB + k0);
    float4 f1 = *reinterpret_cast<const float4*>(gB + k0 + 4);
    float4 f2 = *reinterpret_cast<const float4*>(gB + k0 + 8);
    float4 f3 = *reinterpret_cast<const float4*>(gB + k0 + 12);
    u16x8 blo = { f2bf(f0.x), f2bf(f0.y), f2bf(f0.z), f2bf(f0.w),
                  f2bf(f1.x), f2bf(f1.y), f2bf(f1.z), f2bf(f1.w) };
    u16x8 bhi = { f2bf(f2.x), f2bf(f2.y), f2bf(f2.z), f2bf(f2.w),
                  f2bf(f3.x), f2bf(f3.y), f2bf(f3.z), f2bf(f3.w) };
    *reinterpret_cast<u16x8*>(&Bs[srow * 64 + swz8(srow, sc2)     * 8]) = blo;
    *reinterpret_cast<u16x8*>(&Bs[srow * 64 + swz8(srow, sc2 + 1) * 8]) = bhi;
    __syncthreads();
#pragma unroll
    for (int s = 0; s < 2; ++s) {
      const int ck = s * 4 + h8;   // this lane's k-chunk within the 64-wide tile
      bf16x8 a0 = *reinterpret_cast<const bf16x8*>(&As[(wr + lc)      * 64 + swz8(wr + lc,      ck) * 8]);
      bf16x8 a1 = *reinterpret_cast<const bf16x8*>(&As[(wr + 16 + lc) * 64 + swz8(wr + 16 + lc, ck) * 8]);
      bf16x8 b0 = *reinterpret_cast<const bf16x8*>(&Bs[(wc + lc)      * 64 + swz8(wc + lc,      ck) * 8]);
      bf16x8 b1 = *reinterpret_cast<const bf16x8*>(&Bs[(wc + 16 + lc) * 64 + swz8(wc + 16 + lc, ck) * 8]);
      acc[0][0] = __builtin_amdgcn_mfma_f32_16x16x32_bf16(a0, b0, acc[0][0], 0, 0, 0);
      acc[0][1] = __builtin_amdgcn_mfma_f32_16x16x32_bf16(a0, b1, acc[0][1], 0, 0, 0);
      acc[1][0] = __builtin_amdgcn_mfma_f32_16x16x32_bf16(a1, b0, acc[1][0], 0, 0, 0);
      acc[1][1] = __builtin_amdgcn_mfma_f32_16x16x32_bf16(a1, b1, acc[1][1], 0, 0, 0);
    }
    __syncthreads();
  }

  // C/D layout: col = lane&15, row = (lane>>4)*4 + reg
#pragma unroll
  for (int fi = 0; fi < 2; ++fi)
#pragma unroll
    for (int fj = 0; fj < 2; ++fj) {
      const int col = n0 + wc + fj * 16 + lc;
      const float bv = bias[col];
      const int rbase = m0 + wr + fi * 16 + h8 * 4;
#pragma unroll
      for (int j = 0; j < 4; ++j) {
        const int row = rbase + j;
        float v = acc[fi][fj][j] + bv;
        if (MODE == 1) {
          v += E[(size_t)row * DIM + col];
          v = fmaxf(v, 0.f);
          Ch[(size_t)row * DIM + col] = f2bf(v);
        } else {
          Cf[(size_t)row * Nn + col] = v;
        }
      }
    }
}

// ---- grouped edge GEMM v3: W slice resident in LDS (full-K, swizzled),
// A-fragments loaded DIRECTLY from global (L2/L3-resident h), no barriers in
// the m-loop. Grid (group, n-tile, z=2 m-split) = 640 blocks. BM=128, each of
// 4 waves owns 32 unique A-rows -> acc[2][4] per wave.
__global__ __launch_bounds__(256) void k_edge(
    const u16* __restrict__ h, const float* __restrict__ Wrel,
    const float* __restrict__ brel,
    const int* __restrict__ dep, const int* __restrict__ gov,
    const int* __restrict__ elist, const int* __restrict__ off,
    float* __restrict__ out)
{
  const int g  = blockIdx.x;            // 0..39
  const int n0 = blockIdx.y * 64;
  const int zz = blockIdx.z;            // 0..1 m-interleave
  const int r = (g < NREL) ? g : g - NREL;
  const int base = off[r];
  const int cnt  = off[r + 1] - base;
  if (cnt <= 0) return;
  const bool fwd = (g < NREL);
  const int wsel = fwd ? r : NREL + r;
  const int* gsrc = fwd ? gov : dep;
  const int* gdst = fwd ? dep : gov;

  __shared__ u16 Bs[64 * DIM];          // 64 KB, full-K W slice, swizzled

  const int t = threadIdx.x;
  const int w = t >> 6, l = t & 63;
  const int lc = l & 15, h8 = l >> 4;
  const int srow = t >> 2, sc2 = (t & 3) * 2;

  // stage B once: fp32 W -> bf16 -> LDS (swizzled 16B chunks)
  const float* gB = Wrel + (size_t)wsel * DIM * DIM + (size_t)(n0 + srow) * DIM;
  for (int kc = 0; kc < DIM; kc += 64) {
    const float* p = gB + kc + sc2 * 8;
    float4 f0 = *reinterpret_cast<const float4*>(p);
    float4 f1 = *reinterpret_cast<const float4*>(p + 4);
    float4 f2 = *reinterpret_cast<const float4*>(p + 8);
    float4 f3 = *reinterpret_cast<const float4*>(p + 12);
    u16x8 blo = { f2bf(f0.x), f2bf(f0.y), f2bf(f0.z), f2bf(f0.w),
                  f2bf(f1.x), f2bf(f1.y), f2bf(f1.z), f2bf(f1.w) };
    u16x8 bhi = { f2bf(f2.x), f2bf(f2.y), f2bf(f2.z), f2bf(f2.w),
                  f2bf(f3.x), f2bf(f3.y), f2bf(f3.z), f2bf(f3.w) };
    const int c0 = (kc >> 3) + sc2;
    *reinterpret_cast<u16x8*>(&Bs[srow * DIM + ((c0)     ^ (srow & 7)) * 8]) = blo;
    *reinterpret_cast<u16x8*>(&Bs[srow * DIM + ((c0 + 1) ^ (srow & 7)) * 8]) = bhi;
  }
  float bv[4];
#pragma unroll
  for (int fj = 0; fj < 4; ++fj)
    bv[fj] = brel[(size_t)wsel * DIM + n0 + fj * 16 + lc];
  __syncthreads();   // the ONLY barrier

  const int wr = w * 32;   // wave owns rows wr..wr+31 of the 128-row m-tile
  for (int m0 = zz * 128; m0 < cnt; m0 += 256) {
    const int mcnt = min(128, cnt - m0);
    // per-lane A source rows (guarded; invalid rows -> row 0, never scattered)
    const int ra0 = wr + lc, ra1 = wr + 16 + lc;
    const int e0 = (ra0 < mcnt) ? elist[base + m0 + ra0] : 0;
    const int e1 = (ra1 < mcnt) ? elist[base + m0 + ra1] : 0;
    const u16* pa0 = h + (size_t)gsrc[e0] * DIM + h8 * 8;
    const u16* pa1 = h + (size_t)gsrc[e1] * DIM + h8 * 8;

    f32x4 acc[2][4] = {};
#pragma unroll
    for (int k0 = 0; k0 < DIM; k0 += 32) {
      bf16x8 a0 = *reinterpret_cast<const bf16x8*>(pa0 + k0);
      bf16x8 a1 = *reinterpret_cast<const bf16x8*>(pa1 + k0);
      const int ck = (k0 >> 3) + h8;
#pragma unroll
      for (int fj = 0; fj < 4; ++fj) {
        const int rb = fj * 16 + lc;
        bf16x8 b = *reinterpret_cast<const bf16x8*>(&Bs[rb * DIM + (ck ^ (rb & 7)) * 8]);
        acc[0][fj] = __builtin_amdgcn_mfma_f32_16x16x32_bf16(a0, b, acc[0][fj], 0, 0, 0);
        acc[1][fj] = __builtin_amdgcn_mfma_f32_16x16x32_bf16(a1, b, acc[1][fj], 0, 0, 0);
      }
    }

    // scatter-add: D row = (lane>>4)*4 + reg (+16*fi +wr), col = lane&15 (+16*fj)
#pragma unroll
    for (int fi = 0; fi < 2; ++fi)
#pragma unroll
      for (int j = 0; j < 4; ++j) {
        const int rd = wr + fi * 16 + h8 * 4 + j;
        if (rd < mcnt) {
          const int ed = elist[base + m0 + rd];
          const int dst = gdst[ed];
          float* po = out + (size_t)dst * DIM + n0 + lc;
#pragma unroll
          for (int fj = 0; fj < 4; ++fj)
            unsafeAtomicAdd(po + fj * 16, acc[fi][fj][j] + bv[fj]);
        }
      }
  }
}

extern "C" void kernel_launch(void* const* d_in, const int* in_sizes, int n_in,
                              void* d_out, int out_size, void* d_ws, size_t ws_size,
                              hipStream_t stream) {
  const float* x      = (const float*)d_in[0];
  const int*   dep    = (const int*)d_in[1];
  const int*   rel    = (const int*)d_in[2];
  const int*   gov    = (const int*)d_in[3];
  const float* W_self = (const float*)d_in[4];
  const float* b_self = (const float*)d_in[5];
  const float* W_rel  = (const float*)d_in[6];
  const float* b_rel  = (const float*)d_in[7];
  const float* W_ff   = (const float*)d_in[8];
  const float* b_ff   = (const float*)d_in[9];
  float* out = (float*)d_out;

  char* ws = (char*)d_ws;
  size_t o = 0;
  auto alloc = [&](size_t bytes) -> void* {
    void* p = ws + o;
    o = (o + bytes + 255) & ~(size_t)255;
    return p;
  };
  u16*   hb0   = (u16*)alloc((size_t)N_TOK * DIM * 2);
  u16*   hb1   = (u16*)alloc((size_t)N_TOK * DIM * 2);
  float* outf  = (float*)alloc((size_t)N_TOK * DIM * 4);
  int*   cnt   = (int*)alloc(NREL * 4);
  int*   offs  = (int*)alloc((NREL + 1) * 4);
  int*   cur   = (int*)alloc(NREL * 4);
  int*   elist = (int*)alloc(N_TOK * 4);
  (void)ws_size; (void)in_sizes; (void)n_in; (void)out_size;

  // bucket edges by relation
  hipMemsetAsync(cnt, 0, NREL * 4, stream);
  hipMemsetAsync(cur, 0, NREL * 4, stream);
  k_hist<<<N_TOK / 256, 256, 0, stream>>>(rel, cnt);
  k_scan<<<1, 64, 0, stream>>>(cnt, offs);
  k_fill<<<N_TOK / 256, 256, 0, stream>>>(rel, offs, cur, elist);

  // h0 = bf16(x)
  k_cvt<<<2048, 256, 0, stream>>>(x, hb0, N_TOK * DIM / 4);

  u16* hin = hb0;
  u16* hout = hb1;
  for (int l = 0; l < 2; ++l) {
    hipMemsetAsync(outf, 0, (size_t)N_TOK * DIM * 4, stream);
    dim3 ge(NGRP, DIM / 64, 2);
    k_edge<<<ge, 256, 0, stream>>>(hin, W_rel + (size_t)l * NGRP * DIM * DIM,
                                   b_rel + (size_t)l * NGRP * DIM,
                                   dep, gov, elist, offs, outf);
    dim3 gg(N_TOK / 64, DIM / 64);
    k_gemm<1><<<gg, 256, 0, stream>>>(hin, W_self + (size_t)l * DIM * DIM,
                                      b_self + (size_t)l * DIM, outf,
                                      nullptr, hout, DIM);
    u16* tmp = hin; hin = hout; hout = tmp;
  }

  dim3 gf(N_TOK / 64, OUTD / 64);
  k_gemm<0><<<gf, 256, 0, stream>>>(hin, W_ff, b_ff, nullptr, out, nullptr, OUTD);
}

// Round 7
// 362.553 us; speedup vs baseline: 1.1295x; 1.1295x over previous
//
#include <hip/hip_runtime.h>

#define N_TOK 8192
#define DIM   512
#define NREL  20
#define NGRP  40          // 2R segments (0..19 fwd, 20..39 rev)
#define OUTD  256
#define MAXT  168         // max padded m-tiles: 8192/128 + 20 per direction
#define MAXP  (MAXT*128)  // max padded message rows

typedef unsigned short u16;
typedef u16    u16x8  __attribute__((ext_vector_type(8)));
typedef __bf16 bf16x8 __attribute__((ext_vector_type(8)));
typedef float  f32x4  __attribute__((ext_vector_type(4)));

__device__ __forceinline__ u16 f2bf(float f) {
  union { float f; unsigned u; } v; v.f = f;
  return (u16)((v.u + 0x7FFFu + ((v.u >> 16) & 1u)) >> 16);  // RNE
}

// fp32 -> bf16 (optionally fused ReLU)
__global__ void k_cvt(const float* __restrict__ in, u16* __restrict__ out,
                      int n4, int relu) {
  int stride = gridDim.x * blockDim.x;
  for (int i = blockIdx.x * blockDim.x + threadIdx.x; i < n4; i += stride) {
    float4 v = reinterpret_cast<const float4*>(in)[i];
    if (relu) {
      v.x = fmaxf(v.x, 0.f); v.y = fmaxf(v.y, 0.f);
      v.z = fmaxf(v.z, 0.f); v.w = fmaxf(v.w, 0.f);
    }
    reinterpret_cast<ushort4*>(out)[i] =
        make_ushort4(f2bf(v.x), f2bf(v.y), f2bf(v.z), f2bf(v.w));
  }
}

// ---- padded segment-sorted message list construction ----
__global__ void k_hist(const int* __restrict__ rel, int* __restrict__ cnt) {
  int e = blockIdx.x * blockDim.x + threadIdx.x;
  if (e < N_TOK) atomicAdd(&cnt[rel[e]], 1);
}
// po[s]: padded start of segment s; segtab[tile]: segment id or -1
__global__ void k_scan2(const int* __restrict__ cnt, int* __restrict__ po,
                        int* __restrict__ segtab) {
  if (threadIdx.x == 0) {
    int tile = 0, p = 0;
    for (int s = 0; s < NGRP; ++s) {
      int r = (s < NREL) ? s : s - NREL;
      po[s] = p;
      int nt = (cnt[r] + 127) >> 7;
      for (int i = 0; i < nt; ++i) segtab[tile++] = s;
      p += nt << 7;
    }
    po[NGRP] = p;
    for (; tile < MAXT; ++tile) segtab[tile] = -1;
  }
}
__global__ void k_fill2(const int* __restrict__ rel, const int* __restrict__ dep,
                        const int* __restrict__ gov, const int* __restrict__ po,
                        int* __restrict__ cur, int* __restrict__ msrc,
                        int* __restrict__ mdst) {
  int e = blockIdx.x * blockDim.x + threadIdx.x;
  if (e < N_TOK) {
    int r = rel[e];
    int p = atomicAdd(&cur[r], 1);
    int pf = po[r] + p, pb = po[NREL + r] + p;
    msrc[pf] = gov[e]; mdst[pf] = dep[e];   // fwd: dep += W_r h[gov]
    msrc[pb] = dep[e]; mdst[pb] = gov[e];   // rev: gov += W_{R+r} h[dep]
  }
}

// ---- unified 128x128-tile bf16 MFMA GEMM ----
// KIND 0: Cf[m0+row][col] = acc + bias[col]           (A rows direct)
// KIND 1: gather A rows via msrc (pad -> 0); scatter  Cf[mdst[row]] += acc + bias[seg*DIM+col]
template <int KIND>
__global__ __launch_bounds__(256) void k_mm(
    const u16* __restrict__ A, const u16* __restrict__ Wb,
    const float* __restrict__ bias,
    const int* __restrict__ msrc, const int* __restrict__ mdst,
    const int* __restrict__ segtab,
    float* __restrict__ Cf, int Nn)
{
  int seg = 0;
  if (KIND == 1) { seg = segtab[blockIdx.x]; if (seg < 0) return; }
  const int m0 = blockIdx.x * 128, n0 = blockIdx.y * 128;
  const u16* Bsrc = Wb + (KIND == 1 ? (size_t)seg * DIM * DIM : 0);

  __shared__ u16 As[128 * 64];   // 16 KB, 16B chunks XOR-swizzled by row&7
  __shared__ u16 Bs[128 * 64];

  const int t = threadIdx.x, w = t >> 6, l = t & 63;
  const int wm = (w >> 1) * 64, wn = (w & 1) * 64;   // wave quadrant (64x64)
  const int lc = l & 15, h8 = l >> 4;
  const int wch = (t & 7) ^ ((t >> 3) & 7);          // swizzled write chunk

  // staging: 8 lanes/row (128B contiguous per row), 4 row-passes of 32
  const u16* gApt[4]; const u16* gBpt[4]; bool azero[4];
#pragma unroll
  for (int p = 0; p < 4; ++p) {
    const int row = p * 32 + (t >> 3);
    int arow;
    if (KIND == 1) { arow = msrc[m0 + row]; azero[p] = (arow < 0); if (arow < 0) arow = 0; }
    else { arow = m0 + row; azero[p] = false; }
    gApt[p] = A + (size_t)arow * DIM + (t & 7) * 8;
    gBpt[p] = Bsrc + (size_t)(n0 + row) * DIM + (t & 7) * 8;
  }

  f32x4 acc[4][4] = {};

  for (int k0 = 0; k0 < DIM; k0 += 64) {
#pragma unroll
    for (int p = 0; p < 4; ++p) {
      const int row = p * 32 + (t >> 3);
      u16x8 av = {0, 0, 0, 0, 0, 0, 0, 0};
      if (KIND != 1 || !azero[p]) av = *reinterpret_cast<const u16x8*>(gApt[p] + k0);
      *reinterpret_cast<u16x8*>(&As[row * 64 + wch * 8]) = av;
      u16x8 bw = *reinterpret_cast<const u16x8*>(gBpt[p] + k0);
      *reinterpret_cast<u16x8*>(&Bs[row * 64 + wch * 8]) = bw;
    }
    __syncthreads();
#pragma unroll
    for (int ks = 0; ks < 2; ++ks) {
      const int rc = ks * 4 + h8;
      bf16x8 af[4], bfr[4];
#pragma unroll
      for (int mi = 0; mi < 4; ++mi)
        af[mi] = *reinterpret_cast<const bf16x8*>(&As[(wm + mi * 16 + lc) * 64 + (rc ^ (lc & 7)) * 8]);
#pragma unroll
      for (int ni = 0; ni < 4; ++ni)
        bfr[ni] = *reinterpret_cast<const bf16x8*>(&Bs[(wn + ni * 16 + lc) * 64 + (rc ^ (lc & 7)) * 8]);
#pragma unroll
      for (int mi = 0; mi < 4; ++mi)
#pragma unroll
        for (int ni = 0; ni < 4; ++ni)
          acc[mi][ni] = __builtin_amdgcn_mfma_f32_16x16x32_bf16(af[mi], bfr[ni], acc[mi][ni], 0, 0, 0);
    }
    __syncthreads();
  }

  // C/D layout (verified): col = lane&15, row = (lane>>4)*4 + reg
  float bv[4];
  const float* bb = (KIND == 1) ? (bias + (size_t)seg * DIM) : bias;
#pragma unroll
  for (int ni = 0; ni < 4; ++ni) bv[ni] = bb[n0 + wn + ni * 16 + lc];

#pragma unroll
  for (int mi = 0; mi < 4; ++mi)
#pragma unroll
    for (int j = 0; j < 4; ++j) {
      const int rloc = wm + mi * 16 + h8 * 4 + j;
      if (KIND == 1) {
        const int dst = mdst[m0 + rloc];
        if (dst >= 0) {
          float* pout = Cf + (size_t)dst * DIM + n0 + wn + lc;
#pragma unroll
          for (int ni = 0; ni < 4; ++ni)
            unsafeAtomicAdd(pout + ni * 16, acc[mi][ni][j] + bv[ni]);
        }
      } else {
        float* pout = Cf + (size_t)(m0 + rloc) * Nn + n0 + wn + lc;
#pragma unroll
        for (int ni = 0; ni < 4; ++ni)
          pout[ni * 16] = acc[mi][ni][j] + bv[ni];
      }
    }
}

extern "C" void kernel_launch(void* const* d_in, const int* in_sizes, int n_in,
                              void* d_out, int out_size, void* d_ws, size_t ws_size,
                              hipStream_t stream) {
  const float* x      = (const float*)d_in[0];
  const int*   dep    = (const int*)d_in[1];
  const int*   rel    = (const int*)d_in[2];
  const int*   gov    = (const int*)d_in[3];
  const float* W_self = (const float*)d_in[4];
  const float* b_self = (const float*)d_in[5];
  const float* W_rel  = (const float*)d_in[6];
  const float* b_rel  = (const float*)d_in[7];
  const float* W_ff   = (const float*)d_in[8];
  const float* b_ff   = (const float*)d_in[9];
  float* out = (float*)d_out;

  char* ws = (char*)d_ws;
  size_t o = 0;
  auto alloc = [&](size_t bytes) -> void* {
    void* p = ws + o;
    o = (o + bytes + 255) & ~(size_t)255;
    return p;
  };
  u16*   Wrel_bf  = (u16*)alloc((size_t)2 * NGRP * DIM * DIM * 2);
  u16*   Wself_bf = (u16*)alloc((size_t)2 * DIM * DIM * 2);
  u16*   Wff_bf   = (u16*)alloc((size_t)OUTD * DIM * 2);
  u16*   hb0      = (u16*)alloc((size_t)N_TOK * DIM * 2);
  u16*   hb1      = (u16*)alloc((size_t)N_TOK * DIM * 2);
  float* outf     = (float*)alloc((size_t)N_TOK * DIM * 4);
  int*   cnt      = (int*)alloc(NREL * 4);
  int*   po       = (int*)alloc((NGRP + 1) * 4);
  int*   cur      = (int*)alloc(NREL * 4);
  int*   msrc     = (int*)alloc(MAXP * 4);
  int*   mdst     = (int*)alloc(MAXP * 4);
  int*   segtab   = (int*)alloc(MAXT * 4);
  (void)ws_size; (void)in_sizes; (void)n_in; (void)out_size;

  // weights + input -> bf16 (once)
  k_cvt<<<2048, 256, 0, stream>>>(W_rel,  Wrel_bf,  2 * NGRP * DIM * DIM / 4, 0);
  k_cvt<<<512,  256, 0, stream>>>(W_self, Wself_bf, 2 * DIM * DIM / 4, 0);
  k_cvt<<<128,  256, 0, stream>>>(W_ff,   Wff_bf,   OUTD * DIM / 4, 0);
  k_cvt<<<2048, 256, 0, stream>>>(x, hb0, N_TOK * DIM / 4, 0);

  // padded message list
  hipMemsetAsync(cnt, 0, NREL * 4, stream);
  hipMemsetAsync(cur, 0, NREL * 4, stream);
  hipMemsetAsync(msrc, 0xFF, MAXP * 4, stream);
  hipMemsetAsync(mdst, 0xFF, MAXP * 4, stream);
  k_hist<<<N_TOK / 256, 256, 0, stream>>>(rel, cnt);
  k_scan2<<<1, 64, 0, stream>>>(cnt, po, segtab);
  k_fill2<<<N_TOK / 256, 256, 0, stream>>>(rel, dep, gov, po, cur, msrc, mdst);

  u16* hin = hb0;
  u16* hout = hb1;
  for (int l = 0; l < 2; ++l) {
    // self transform writes outf = h @ Ws^T + bs  (fp32, no memset needed)
    k_mm<0><<<dim3(64, 4), 256, 0, stream>>>(
        hin, Wself_bf + (size_t)l * DIM * DIM, b_self + (size_t)l * DIM,
        nullptr, nullptr, nullptr, outf, DIM);
    // edge messages: outf[dst] += h[src] @ Wr^T + br  (atomic)
    k_mm<1><<<dim3(MAXT, 4), 256, 0, stream>>>(
        hin, Wrel_bf + (size_t)l * NGRP * DIM * DIM,
        b_rel + (size_t)l * NGRP * DIM, msrc, mdst, segtab, outf, DIM);
    // h_{l+1} = bf16(relu(outf))
    k_cvt<<<2048, 256, 0, stream>>>(outf, hout, N_TOK * DIM / 4, 1);
    u16* tmp = hin; hin = hout; hout = tmp;
  }

  // final FF (fp32 out)
  k_mm<0><<<dim3(64, 2), 256, 0, stream>>>(
      hin, Wff_bf, b_ff, nullptr, nullptr, nullptr, out, OUTD);
}